// Round 4
// baseline (128.994 us; speedup 1.0000x reference)
//
#include <hip/hip_runtime.h>

// YOLO loss: S=1024, 30 f32 channels/cell, channel-last contiguous.
// loss = 5*xy + 5*box + (conf_t-conf_p)^2 + cls_masked
//
// R1: coalesced LDS staging fixed 3.25x over-fetch (236 -> 46.8us).
// R2: occupancy 19->42% but flat (45.2us) -> barrier convoy, not occupancy.
// R3: wave-private pipeline. Each wave stages ONLY its own 32 cells' data
// into its own LDS region and computes from it -> NO __syncthreads at all.
// Next tile's global loads issue before compute (T14 issue-early), so loads
// stay in flight through the compute phase; waves free-run and de-convoy.

constexpr int S_DIM      = 1024;
constexpr int NCELL      = S_DIM * S_DIM;        // 1,048,576
constexpr int CH         = 30;
constexpr int BLOCK      = 256;
constexpr int TILE_CELLS = 128;                  // 32 cells per wave
constexpr int TILE_F4    = TILE_CELLS * CH / 4;  // 960 float4 per tensor
constexpr int WAVE_F4    = TILE_F4 / 4;          // 240 float4 per wave per tensor
constexpr int NTILES     = NCELL / TILE_CELLS;   // 8192
constexpr int GRID       = 2048;                 // 4 tiles per block

__device__ __forceinline__ float wave_reduce_sum(float v) {
#pragma unroll
    for (int off = 32; off > 0; off >>= 1)
        v += __shfl_down(v, off, 64);
    return v;
}

__global__ __launch_bounds__(BLOCK, 4) void yolo_partial_kernel(
        const float* __restrict__ pred,
        const float* __restrict__ tgt,
        float* __restrict__ partial) {
    // 30KB LDS: pred f4 [0,960), tgt f4 [960,1920). Wave w owns f4
    // [w*240, (w+1)*240) of each tensor = cells [w*32, w*32+32).
    __shared__ float4 smem4[2 * TILE_F4];
    float* s = reinterpret_cast<float*>(smem4);

    const int tid  = threadIdx.x;
    const int wv   = tid >> 6;
    const int ln   = tid & 63;
    const int half = ln & 1;          // which box / class half
    const int cl   = ln >> 1;         // wave-local cell 0..31

    const float4* gp4 = reinterpret_cast<const float4*>(pred);
    const float4* gt4 = reinterpret_cast<const float4*>(tgt);

    // Fixed per-lane LDS float bases (wave-private region, same every tile).
    const int pbase = wv * (WAVE_F4 * 4) + cl * CH;            // pred floats
    const int tbase = TILE_F4 * 4 + wv * (WAVE_F4 * 4) + cl * CH;
    const int lbase = wv * WAVE_F4 + ln;                       // f4 write slot

    float4 rp[4], rt[4];

    int tile = blockIdx.x;
    {   // prologue: issue tile0 loads (lane-contiguous: fully coalesced)
        const size_t g = (size_t)tile * TILE_F4 + wv * WAVE_F4 + ln;
#pragma unroll
        for (int j = 0; j < 4; ++j)
            if (j * 64 + ln < WAVE_F4) { rp[j] = gp4[g + j * 64]; rt[j] = gt4[g + j * 64]; }
    }

    float acc = 0.0f;
    for (; tile < NTILES; tile += GRID) {
        // order: prev tile's LDS reads must not be passed by these writes
        asm volatile("s_waitcnt lgkmcnt(0)" ::: "memory");

        // stage regs -> wave-private LDS (vmcnt wait auto-inserted via data dep)
#pragma unroll
        for (int j = 0; j < 4; ++j)
            if (j * 64 + ln < WAVE_F4) {
                smem4[lbase + j * 64]           = rp[j];
                smem4[TILE_F4 + lbase + j * 64] = rt[j];
            }

        // issue NEXT tile's loads now -> in flight during compute below
        const int ntile = tile + GRID;
        if (ntile < NTILES) {
            const size_t g = (size_t)ntile * TILE_F4 + wv * WAVE_F4 + ln;
#pragma unroll
            for (int j = 0; j < 4; ++j)
                if (j * 64 + ln < WAVE_F4) { rp[j] = gp4[g + j * 64]; rt[j] = gt4[g + j * 64]; }
        }

        // drain our ds_writes; wave lockstep => whole wave's region is ready
        asm volatile("s_waitcnt lgkmcnt(0)" ::: "memory");

        const float* pp = s + pbase;
        const float* tt = s + tbase;

        // this thread's box: channels [5*half .. 5*half+4] = (conf,x,y,w,h)
        {
            const int o = 5 * half;
            const float conf_p = pp[o + 0];
            const float x_p    = pp[o + 1];
            const float y_p    = pp[o + 2];
            const float w_p    = sqrtf(fabsf(pp[o + 3]));
            const float h_p    = sqrtf(fabsf(pp[o + 4]));
            const float conf_t = tt[o + 0];
            const float x_t    = tt[o + 1];
            const float y_t    = tt[o + 2];
            const float w_t    = sqrtf(tt[o + 3]);
            const float h_t    = sqrtf(tt[o + 4]);

            const float dx = x_t - x_p, dy = y_t - y_p;
            const float dw = w_t - w_p, dh = h_t - h_p;
            const float dc = conf_t - conf_p;

            acc += 5.0f * ((dx * dx + dy * dy) * conf_t)
                 + 5.0f * ((dw * dw + dh * dh) * conf_t)
                 + dc * dc;
        }

        // this thread's class half: channels [10+10*half ..+9]; mask needs
        // the FULL 20-channel target sum -> combine across the lane pair.
        {
            float ssum = 0.0f, per_cell = 0.0f;
            const int co = 10 + 10 * half;
#pragma unroll
            for (int k = 0; k < 10; ++k) {
                const float tc = tt[co + k];
                const float pc = pp[co + k];
                ssum     += tc;
                per_cell += tc * tc - pc * pc;
            }
            const float tot = ssum + __shfl_xor(ssum, 1, 64);
            acc += (tot == 1.0f) ? per_cell : 0.0f;
        }
    }

    // per-wave reduction only (no cross-wave LDS, no barrier)
    float v = wave_reduce_sum(acc);
    if (ln == 0) partial[wv * GRID + blockIdx.x] = v;   // coalesced final reads
}

__global__ __launch_bounds__(256) void yolo_final_kernel(
        const float* __restrict__ partial,
        float* __restrict__ out,
        int n) {
    float acc = 0.0f;
    for (int i = threadIdx.x; i < n; i += 256)
        acc += partial[i];

    __shared__ float red[4];
    const int lane = threadIdx.x & 63;
    const int wid  = threadIdx.x >> 6;
    float v = wave_reduce_sum(acc);
    if (lane == 0) red[wid] = v;
    __syncthreads();
    if (wid == 0) {
        v = (lane < 4) ? red[lane] : 0.0f;
        v = wave_reduce_sum(v);
        if (lane == 0) out[0] = v;
    }
}

extern "C" void kernel_launch(void* const* d_in, const int* in_sizes, int n_in,
                              void* d_out, int out_size, void* d_ws, size_t ws_size,
                              hipStream_t stream) {
    const float* pred = (const float*)d_in[0];
    const float* tgt  = (const float*)d_in[1];
    float* out        = (float*)d_out;
    float* partial    = (float*)d_ws;   // 4*GRID floats = 32 KB

    yolo_partial_kernel<<<GRID, BLOCK, 0, stream>>>(pred, tgt, partial);
    yolo_final_kernel<<<1, 256, 0, stream>>>(partial, out, 4 * GRID);
}

// Round 7
// 101.039 us; speedup vs baseline: 1.2767x; 1.2767x over previous
//
#include <hip/hip_runtime.h>

// YOLO loss: S=1024, 30 f32 channels/cell, channel-last contiguous.
// loss = 5*xy + 5*box + (conf_t-conf_p)^2 + cls_masked
//
// R1: coalesced LDS staging fixed 3.25x over-fetch (236 -> 46.8us).
// R2: occupancy 19->42% flat (45.2us) -> convoy/latency, not occupancy.
// R4: reg-prefetch w/ divergent guards + asm clobbers spilled (129us).
// R5/R6: global_load_lds pipeline NaN'd twice (unvalidated construct) -> drop.
// R7: verified constructs only. Double-buffered LDS + cross-tile register
// prefetch: load tile k+1 into regs (uniform 8/8/7/7 wave split, fully
// unrolled, no divergence), compute tile k from LDS, ds_write regs, ONE
// __syncthreads per tile. HBM latency hides under compute.

constexpr int CH         = 30;
constexpr int NCELL      = 1024 * 1024;
constexpr int BLOCK      = 256;
constexpr int TILE_CELLS = 128;
constexpr int TILE_F4    = TILE_CELLS * CH / 4;   // 960 float4 per tensor
constexpr int GRID       = 512;                   // 2 blocks/CU resident
constexpr int NTILES     = NCELL / TILE_CELLS;    // 8192
constexpr int NIT        = NTILES / GRID;         // 16 tiles per block

__device__ __forceinline__ float wave_reduce_sum(float v) {
#pragma unroll
    for (int off = 32; off > 0; off >>= 1)
        v += __shfl_down(v, off, 64);
    return v;
}

__global__ __launch_bounds__(BLOCK) void yolo_partial_kernel(
        const float* __restrict__ pred,
        const float* __restrict__ tgt,
        float* __restrict__ partial) {
    // [buffer][pred f4 0..959 | tgt f4 960..1919] : 61,440 B -> 2 blocks/CU
    __shared__ float4 sbuf[2][2 * TILE_F4];

    const int tid  = threadIdx.x;
    const int wv   = tid >> 6;
    const int ln   = tid & 63;
    const int cell = tid >> 1;        // 0..127
    const int half = tid & 1;         // which box / class half

    const float4* pf4 = reinterpret_cast<const float4*>(pred);
    const float4* tf4 = reinterpret_cast<const float4*>(tgt);

    // Staging split over the combined 1920-f4 tile in 64-f4 chunks:
    // wave0 chunks 0..7, wave1 8..15, wave2 16..22, wave3 23..29 (8,8,7,7).
    // Chunk boundaries are multiples of 64 and 960 is a multiple of 64, so
    // every chunk lies entirely in one tensor -> branch-free after unroll.
    const int c0 = (wv < 2) ? wv * 8 : 16 + (wv - 2) * 7;

    float4 r[8];

    auto load_tile = [&](int tile) {
        const size_t tb = (size_t)tile * TILE_F4;
        if (wv < 2) {
#pragma unroll
            for (int k = 0; k < 8; ++k) {
                const int ci = (c0 + k) * 64;
                r[k] = (ci < TILE_F4) ? pf4[tb + ci + ln]
                                      : tf4[tb + (ci - TILE_F4) + ln];
            }
        } else {
#pragma unroll
            for (int k = 0; k < 7; ++k) {
                const int ci = (c0 + k) * 64;   // >= 1024 -> always tgt
                r[k] = tf4[tb + (ci - TILE_F4) + ln];
            }
        }
    };
    auto store_tile = [&](int b) {
        if (wv < 2) {
#pragma unroll
            for (int k = 0; k < 8; ++k) sbuf[b][(c0 + k) * 64 + ln] = r[k];
        } else {
#pragma unroll
            for (int k = 0; k < 7; ++k) sbuf[b][(c0 + k) * 64 + ln] = r[k];
        }
    };

    int t = blockIdx.x;
    load_tile(t);          // prologue: tile 0 -> regs -> buf0
    store_tile(0);
    __syncthreads();

    float acc = 0.0f;
    for (int it = 0; it < NIT; ++it) {
        const int cur = it & 1;
        const bool havenext = (it + 1 < NIT);

        if (havenext) load_tile(t + GRID);      // issue early: hides under compute
        __builtin_amdgcn_sched_barrier(0);       // keep loads above compute

        const float* bf = reinterpret_cast<const float*>(&sbuf[cur][0]);
        const float* pp = bf + cell * CH;
        const float* tt = bf + TILE_F4 * 4 + cell * CH;

        // this thread's box: channels [5*half .. 5*half+4] = (conf,x,y,w,h)
        {
            const int o = 5 * half;
            const float conf_p = pp[o + 0];
            const float x_p    = pp[o + 1];
            const float y_p    = pp[o + 2];
            const float w_p    = sqrtf(fabsf(pp[o + 3]));
            const float h_p    = sqrtf(fabsf(pp[o + 4]));
            const float conf_t = tt[o + 0];
            const float x_t    = tt[o + 1];
            const float y_t    = tt[o + 2];
            const float w_t    = sqrtf(tt[o + 3]);
            const float h_t    = sqrtf(tt[o + 4]);

            const float dx = x_t - x_p, dy = y_t - y_p;
            const float dw = w_t - w_p, dh = h_t - h_p;
            const float dc = conf_t - conf_p;

            acc += 5.0f * ((dx * dx + dy * dy) * conf_t)
                 + 5.0f * ((dw * dw + dh * dh) * conf_t)
                 + dc * dc;
        }

        // this thread's class half: channels [10+10*half ..+9]; the mask
        // needs the FULL 20-channel target sum -> combine across lane pair.
        {
            float ssum = 0.0f, per_cell = 0.0f;
            const int co = 10 + 10 * half;
#pragma unroll
            for (int k = 0; k < 10; ++k) {
                const float tc = tt[co + k];
                const float pc = pp[co + k];
                ssum     += tc;
                per_cell += tc * tc - pc * pc;
            }
            const float tot = ssum + __shfl_xor(ssum, 1, 64);
            acc += (tot == 1.0f) ? per_cell : 0.0f;
        }

        // stage tile t+GRID into the other buffer. Its previous readers
        // finished before last iteration's barrier -> safe.
        if (havenext) store_tile(cur ^ 1);
        __syncthreads();
        t += GRID;
    }

    // block reduction: wave shuffle -> LDS across 4 waves
    __shared__ float red[BLOCK / 64];
    float v = wave_reduce_sum(acc);
    if (ln == 0) red[wv] = v;
    __syncthreads();
    if (wv == 0) {
        v = (ln < (BLOCK / 64)) ? red[ln] : 0.0f;
        v = wave_reduce_sum(v);
        if (ln == 0) partial[blockIdx.x] = v;
    }
}

__global__ __launch_bounds__(256) void yolo_final_kernel(
        const float* __restrict__ partial,
        float* __restrict__ out,
        int n) {
    float acc = 0.0f;
    for (int i = threadIdx.x; i < n; i += 256)
        acc += partial[i];

    __shared__ float red[4];
    const int lane = threadIdx.x & 63;
    const int wid  = threadIdx.x >> 6;
    float v = wave_reduce_sum(acc);
    if (lane == 0) red[wid] = v;
    __syncthreads();
    if (wid == 0) {
        v = (lane < 4) ? red[lane] : 0.0f;
        v = wave_reduce_sum(v);
        if (lane == 0) out[0] = v;
    }
}

extern "C" void kernel_launch(void* const* d_in, const int* in_sizes, int n_in,
                              void* d_out, int out_size, void* d_ws, size_t ws_size,
                              hipStream_t stream) {
    const float* pred = (const float*)d_in[0];
    const float* tgt  = (const float*)d_in[1];
    float* out        = (float*)d_out;
    float* partial    = (float*)d_ws;   // GRID floats = 2 KB

    yolo_partial_kernel<<<GRID, BLOCK, 0, stream>>>(pred, tgt, partial);
    yolo_final_kernel<<<1, 256, 0, stream>>>(partial, out, GRID);
}